// Round 2
// baseline (449.421 us; speedup 1.0000x reference)
//
#include <hip/hip_runtime.h>
#include <math.h>

// Problem constants
#define BATCH 8192
#define LOD 60
#define LSD 120
#define AD 10
#define NB 15
#define BW 3
#define H 60

// Output layout (floats)
#define NM_SZ (BATCH * LSD)   // next_mean 983040
#define NC_SZ (BATCH * LOD)   // 491520 each for ncu/ncl/ncs

// Geometry: 128 batch-groups (64 batches) x 4 row-groups (15 rows).
// Waves own rows {4,4,4,3}. Exactly 512 blocks = 2 per CU, one round.
#define RG_ROWS 15
#define NJJ 21                      // RG_ROWS + 2*BW
#define VSJ 65
#define VSV (NJJ * VSJ)             // 1365 floats per staged plane
#define VS_FLOATS (5 * VSV)         // 6825
#define PACK_FLOATS (RG_ROWS * NB * 28)   // 6300
#define OVL_FLOATS (VS_FLOATS + PACK_FLOATS)  // 13125 floats = 52.5 KB
#define CS 64                       // coef_s row stride

// phase-1 overlay of ovl: pm_s [120][65]=7800 @0, act_s [10][65]=650 @7800,
// hid_s [60][65]=3900 @8450  (total 12350 <= 13125)
#define PM_OFF  0
#define ACT_OFF 7800
#define HID_OFF 8450

__device__ __forceinline__ float elup1f(float x) {
    return x < 0.0f ? __expf(x) : x + 1.0f;
}

__global__ __launch_bounds__(256, 2) void k_fused(
    const float* __restrict__ pm, const float* __restrict__ cu,
    const float* __restrict__ cl, const float* __restrict__ cs,
    const float* __restrict__ action,
    const float* __restrict__ tm11, const float* __restrict__ tm12,
    const float* __restrict__ tm21, const float* __restrict__ tm22,
    const float* __restrict__ log_noise,
    const float* __restrict__ w_coef, const float* __restrict__ b_coef,
    const float* __restrict__ w_c1, const float* __restrict__ b_c1,
    const float* __restrict__ w_c2, const float* __restrict__ b_c2,
    float* __restrict__ out)
{
    __shared__ float coef_s[NB * CS];                // 3.75 KB
    __shared__ __align__(16) float ovl[OVL_FLOATS];  // 52.5 KB overlaid

    const int tid  = threadIdx.x;
    const int wave = tid >> 6;
    const int lane = tid & 63;
    const int wv   = __builtin_amdgcn_readfirstlane(wave);  // provably uniform

    // XCD-grouped swizzle: HW round-robins bid%8 across XCDs; map so the 4
    // rg-blocks of one bg share bid&7 -> same XCD -> pm tile L2-hot.
    const int bid  = blockIdx.x;
    const int xcd  = bid & 7;
    const int slot = bid >> 3;            // 0..63
    const int bg   = xcd * 16 + (slot >> 2);
    const int rg   = slot & 3;
    const int b0   = bg * 64;
    const int i0   = rg * RG_ROWS;

    // ---------------- phase 1a: stage pm/act ----------------
    float* pm_s  = ovl + PM_OFF;    // [j][b] stride 65 (bank-stride-1 everywhere)
    float* act_s = ovl + ACT_OFF;   // [a][b] stride 65
    float* hid_s = ovl + HID_OFF;   // [h][b] stride 65

    for (int idx = tid; idx < 64 * LSD; idx += 256) {
        int b = idx / LSD, j = idx - b * LSD;       // coalesced global read
        pm_s[j * 65 + b] = pm[(b0 + b) * LSD + j];  // stride-65 lanes: no conflicts
    }
    for (int idx = tid; idx < 64 * AD; idx += 256) {
        int b = idx / AD, a = idx - b * AD;
        act_s[a * 65 + b] = action[(b0 + b) * AD + a];
    }
    __syncthreads();

    // ---------------- phase 1b: logits + hidden layer ----------------
    // logits: wave wv owns k in {wv, wv+4, wv+8, wv+12(<15)}; weight rows are
    // wave-uniform -> s_load on the SMEM pipe.
    {
        const int k3 = (wv < 3) ? wv + 12 : 14;     // dummy for wave 3
        const float* w0 = w_coef + wv * LSD;
        const float* w1 = w_coef + (wv + 4) * LSD;
        const float* w2 = w_coef + (wv + 8) * LSD;
        const float* w3 = w_coef + k3 * LSD;
        float a0 = b_coef[wv], a1 = b_coef[wv + 4], a2 = b_coef[wv + 8];
        float a3 = b_coef[k3];
        #pragma unroll 4
        for (int j = 0; j < LSD; ++j) {
            float p = pm_s[j * 65 + lane];          // lane-stride-1: conflict-free
            a0 = fmaf(p, w0[j], a0);
            a1 = fmaf(p, w1[j], a1);
            a2 = fmaf(p, w2[j], a2);
            a3 = fmaf(p, w3[j], a3);
        }
        coef_s[wv * CS + lane] = a0;
        coef_s[(wv + 4) * CS + lane] = a1;
        coef_s[(wv + 8) * CS + lane] = a2;
        if (wv < 3) coef_s[k3 * CS + lane] = a3;
    }
    // hidden: wave wv owns h in [wv*15, wv*15+15), shared across waves via LDS
    {
        float av[AD];
        #pragma unroll
        for (int a = 0; a < AD; ++a) av[a] = act_s[a * 65 + lane];
        #pragma unroll
        for (int q = 0; q < 15; ++q) {
            int h = wv * 15 + q;
            float acc = b_c1[h];
            #pragma unroll
            for (int a = 0; a < AD; ++a)
                acc = fmaf(av[a], w_c1[h * AD + a], acc);   // uniform -> s_load
            hid_s[h * 65 + lane] = fmaxf(acc, 0.0f);
        }
    }
    __syncthreads();

    // ---------------- phase 1c: softmax + control rows (registers) ----------
    if (tid < 64) {   // wave 0 normalizes while others start the out-dot
        float v[NB];
        float mx = -1e30f;
        #pragma unroll
        for (int k = 0; k < NB; ++k) { v[k] = coef_s[k * CS + tid]; mx = fmaxf(mx, v[k]); }
        float sm = 0.0f;
        #pragma unroll
        for (int k = 0; k < NB; ++k) { v[k] = __expf(v[k] - mx); sm += v[k]; }
        float inv = 1.0f / sm;
        #pragma unroll
        for (int k = 0; k < NB; ++k) coef_s[k * CS + tid] = v[k] * inv;
    }
    // wave wv computes ctrl for exactly the rows its lanes consume in phase 2:
    // upper rows i0+wv*4+q and lower rows 60+i0+wv*4+q (batch = lane matches).
    float ctl[8];
    {
        int rows[4];
        #pragma unroll
        for (int q = 0; q < 4; ++q) {
            int r = i0 + wv * 4 + q;
            rows[q] = (r < LOD) ? r : (LOD - 1);    // wave3 q=3: clamped dummy
        }
        #pragma unroll
        for (int q = 0; q < 4; ++q) {
            ctl[q]     = b_c2[rows[q]];
            ctl[4 + q] = b_c2[LOD + rows[q]];
        }
        #pragma unroll 2
        for (int h = 0; h < H; ++h) {
            float hv = hid_s[h * 65 + lane];        // lane-stride-1
            #pragma unroll
            for (int q = 0; q < 4; ++q) {
                ctl[q]     = fmaf(hv, w_c2[rows[q] * H + h], ctl[q]);         // s_load
                ctl[4 + q] = fmaf(hv, w_c2[(LOD + rows[q]) * H + h], ctl[4 + q]);
            }
        }
    }
    __syncthreads();   // coef final; all reads of pm_s/act_s/hid_s done

    // ---------------- phase 2: stage vs + pack ----------------
    float* vsb    = ovl;                 // [v][jj][b], stride 65
    float* pack_s = ovl + VS_FLOATS;     // [ri][k][jo][m], addr == staging idx

    float cf[NB];
    #pragma unroll
    for (int k = 0; k < NB; ++k) cf[k] = coef_s[k * CS + lane];

    for (int idx = tid; idx < 5 * 64 * NJJ; idx += 256) {
        int v   = idx / (64 * NJJ);
        int rem = idx - v * (64 * NJJ);
        int blc = rem / NJJ;
        int jj  = rem - blc * NJJ;
        int j   = i0 - BW + jj;
        int bb  = b0 + blc;
        float val = 0.0f;
        if (j >= 0 && j < LOD) {
            if (v == 0)      val = pm[bb * LSD + j];
            else if (v == 1) val = pm[bb * LSD + LOD + j];
            else if (v == 2) val = cu[bb * LOD + j];
            else if (v == 3) val = cl[bb * LOD + j];
            else             val = cs[bb * LOD + j];
        }
        vsb[v * VSV + jj * VSJ + blc] = val;       // jj-fastest: bank-stride-1
    }
    // pack: LDS write address == idx  -> pure stride-1, zero conflicts
    for (int idx = tid; idx < PACK_FLOATS; idx += 256) {
        int m  = idx & 3;
        int t  = idx >> 2;
        int jo = t % 7;
        int t2 = t / 7;
        int k  = t2 % NB;
        int ri = t2 / NB;
        int i  = i0 + ri;
        int j  = i - BW + jo;
        const float* tmm = (m == 0) ? tm11 : (m == 1) ? tm12 : (m == 2) ? tm21 : tm22;
        float val = (j >= 0 && j < LOD) ? tmm[k * (LOD * LOD) + i * LOD + j] : 0.0f;
        pack_s[idx] = val;
    }
    __syncthreads();

    // ---------------- phase 2: mixing + banded products ----------------
    const int nrr = (wv < 3) ? 4 : 3;
    float onm[4], onl[4], ouv[4], olv[4], osv[4];
    #pragma unroll
    for (int rr = 0; rr < 4; ++rr) {
        if (rr < nrr) {
            const int riu = wv * 4 + rr;            // wave-uniform
            const int iu  = i0 + riu;

            float t[28];
            #pragma unroll
            for (int z = 0; z < 28; ++z) t[z] = 0.0f;
            const float4* tp = (const float4*)pack_s + riu * (NB * 7);
            #pragma unroll
            for (int k = 0; k < NB; ++k) {
                float c = cf[k];
                #pragma unroll
                for (int jo = 0; jo < 7; ++jo) {
                    float4 tv = tp[k * 7 + jo];     // uniform addr -> broadcast
                    t[jo * 4 + 0] = fmaf(c, tv.x, t[jo * 4 + 0]);
                    t[jo * 4 + 1] = fmaf(c, tv.y, t[jo * 4 + 1]);
                    t[jo * 4 + 2] = fmaf(c, tv.z, t[jo * 4 + 2]);
                    t[jo * 4 + 3] = fmaf(c, tv.w, t[jo * 4 + 3]);
                }
            }
            t[3 * 4 + 0] += 1.0f;    // + eye on t11 at j == i
            t[3 * 4 + 3] += 1.0f;    // + eye on t22 at j == i

            float nmu = 0.f, nml = 0.f, ncuv = 0.f, nclv = 0.f, ncsv = 0.f;
            #pragma unroll
            for (int jo = 0; jo < 7; ++jo) {
                const int jj = riu + jo;
                float m_ = vsb[0 * VSV + jj * VSJ + lane];
                float n_ = vsb[1 * VSV + jj * VSJ + lane];
                float u_ = vsb[2 * VSV + jj * VSJ + lane];
                float l_ = vsb[3 * VSV + jj * VSJ + lane];
                float s_ = vsb[4 * VSV + jj * VSJ + lane];
                float A = t[jo * 4 + 0], Bv = t[jo * 4 + 1];
                float C = t[jo * 4 + 2], D  = t[jo * 4 + 3];
                nmu = fmaf(A, m_, nmu);  nmu = fmaf(Bv, n_, nmu);
                nml = fmaf(C, m_, nml);  nml = fmaf(D, n_, nml);
                float e1 = fmaf(Bv, s_, A * u_);
                float e2 = fmaf(Bv, l_, A * s_);
                float f1 = fmaf(D, s_, C * u_);
                float f2 = fmaf(D, l_, C * s_);
                ncuv = fmaf(A, e1, ncuv);  ncuv = fmaf(Bv, e2, ncuv);
                nclv = fmaf(C, f1, nclv);  nclv = fmaf(D, f2, nclv);
                ncsv = fmaf(C, e1, ncsv);  ncsv = fmaf(D, e2, ncsv);
            }
            ncuv += elup1f(log_noise[iu]);
            nclv += elup1f(log_noise[LOD + iu]);
            nmu  += ctl[rr];
            nml  += ctl[4 + rr];
            onm[rr] = nmu; onl[rr] = nml; ouv[rr] = ncuv; olv[rr] = nclv; osv[rr] = ncsv;
        }
    }
    __syncthreads();   // all reads of pack_s done

    // ---------------- output staging + coalesced flush ----------------
    float* ost = ovl + VS_FLOATS;   // overlays pack: [t][ri][b], plane 975
    #pragma unroll
    for (int rr = 0; rr < 4; ++rr) {
        if (rr < nrr) {
            int ri = wv * 4 + rr;
            ost[0 * 975 + ri * 65 + lane] = onm[rr];
            ost[1 * 975 + ri * 65 + lane] = onl[rr];
            ost[2 * 975 + ri * 65 + lane] = ouv[rr];
            ost[3 * 975 + ri * 65 + lane] = olv[rr];
            ost[4 * 975 + ri * 65 + lane] = osv[rr];
        }
    }
    __syncthreads();

    for (int idx = tid; idx < 5 * 64 * RG_ROWS; idx += 256) {
        int t5  = idx / (64 * RG_ROWS);
        int rem = idx - t5 * (64 * RG_ROWS);
        int blc = rem / RG_ROWS;
        int rq  = rem - blc * RG_ROWS;
        int bb  = b0 + blc;
        float v = ost[t5 * 975 + rq * 65 + blc];    // rq-fastest: bank-stride-1
        float* bp;
        if (t5 == 0)      bp = out + bb * LSD + i0;
        else if (t5 == 1) bp = out + bb * LSD + LOD + i0;
        else if (t5 == 2) bp = out + NM_SZ + bb * LOD + i0;
        else if (t5 == 3) bp = out + NM_SZ + NC_SZ + bb * LOD + i0;
        else              bp = out + NM_SZ + 2 * NC_SZ + bb * LOD + i0;
        bp[rq] = v;                                 // 60B contiguous runs
    }
}

extern "C" void kernel_launch(void* const* d_in, const int* in_sizes, int n_in,
                              void* d_out, int out_size, void* d_ws, size_t ws_size,
                              hipStream_t stream) {
    (void)in_sizes; (void)n_in; (void)out_size; (void)d_ws; (void)ws_size;
    const float* pm        = (const float*)d_in[0];
    const float* cu        = (const float*)d_in[1];
    const float* cl        = (const float*)d_in[2];
    const float* cs        = (const float*)d_in[3];
    const float* action    = (const float*)d_in[4];
    const float* tm11      = (const float*)d_in[5];
    const float* tm12      = (const float*)d_in[6];
    const float* tm21      = (const float*)d_in[7];
    const float* tm22      = (const float*)d_in[8];
    const float* log_noise = (const float*)d_in[9];
    const float* w_coef    = (const float*)d_in[10];
    const float* b_coef    = (const float*)d_in[11];
    const float* w_c1      = (const float*)d_in[12];
    const float* b_c1      = (const float*)d_in[13];
    const float* w_c2      = (const float*)d_in[14];
    const float* b_c2      = (const float*)d_in[15];

    hipLaunchKernelGGL(k_fused, dim3(512), dim3(256), 0, stream,
                       pm, cu, cl, cs, action, tm11, tm12, tm21, tm22,
                       log_noise, w_coef, b_coef, w_c1, b_c1, w_c2, b_c2,
                       (float*)d_out);
}

// Round 3
// 131.395 us; speedup vs baseline: 3.4204x; 3.4204x over previous
//
#include <hip/hip_runtime.h>
#include <math.h>

// Problem constants
#define BATCH 8192
#define LOD 60
#define LSD 120
#define AD 10
#define NB 15
#define BW 3
#define H 60

// Output layout (floats)
#define NM_SZ (BATCH * LSD)   // next_mean 983040
#define NC_SZ (BATCH * LOD)   // 491520 each for ncu/ncl/ncs

// Geometry: 128 batch-groups (64 batches) x 6 row-groups (10 rows) = 768 blocks.
// 256 threads = 4 waves; wave owns rows {3,3,2,2} (unrolled to 3 with clamped
// duplicate rows -> no guarded array writes, benign identical double-stores).
#define RGS 6
#define RG_ROWS 10
#define NJJ 16                       // RG_ROWS + 2*BW = 16  (pow2 decode!)
#define VSJ 65
#define VSV (NJJ * VSJ)              // 1040 floats per staged plane
#define VS_FLOATS (5 * VSV)          // 5200
#define PACK_FLOATS (RG_ROWS * NB * 28)   // 4200
#define OST_PLANE (RG_ROWS * 65)     // 650; ost (3250) overlays pack (4200)
#define OVL2 (VS_FLOATS + PACK_FLOATS)    // 9400 floats = 37.6 KB

__device__ __forceinline__ float elup1f(float x) {
    return x < 0.0f ? __expf(x) : x + 1.0f;
}

__global__ __launch_bounds__(256, 3) void k_fused(
    const float* __restrict__ pm, const float* __restrict__ cu,
    const float* __restrict__ cl, const float* __restrict__ cs,
    const float* __restrict__ action,
    const float* __restrict__ tm11, const float* __restrict__ tm12,
    const float* __restrict__ tm21, const float* __restrict__ tm22,
    const float* __restrict__ log_noise,
    const float* __restrict__ w_coef, const float* __restrict__ b_coef,
    const float* __restrict__ w_c1, const float* __restrict__ b_c1,
    const float* __restrict__ w_c2, const float* __restrict__ b_c2,
    float* __restrict__ out)
{
    __shared__ float coef_s[NB * 64];                // 3.75 KB
    __shared__ __align__(16) float ovl[OVL2];        // 37.6 KB (vs + pack/ost)

    const int tid  = threadIdx.x;
    const int wave = tid >> 6;
    const int lane = tid & 63;
    const int wv   = __builtin_amdgcn_readfirstlane(wave);

    // XCD-grouped swizzle: the 6 rg-blocks of one bg share one XCD's L2.
    const int bid  = blockIdx.x;          // 768 = 8 * 96
    const int xcd  = bid & 7;
    const int slot = bid >> 3;            // 0..95
    const int bg   = xcd * 16 + slot / RGS;
    const int rg   = slot % RGS;
    const int b0   = bg * 64;
    const int i0   = rg * RG_ROWS;

    // ---------------- phase 1a: logits (pm streamed from global) ----------
    // Each lane streams its own batch row (64 rows x 480 B = 30 KB, L1-resident,
    // reused by all 4 waves). Weight rows are wave-uniform -> scalar loads.
    {
        const int k0 = wv, k1 = wv + 4, k2 = wv + 8;
        const int k3 = (wv < 3) ? wv + 12 : 14;      // wave 3: dummy stream
        const float4* pmv = (const float4*)(pm + (size_t)(b0 + lane) * LSD);
        const float4* w0 = (const float4*)(w_coef + k0 * LSD);
        const float4* w1 = (const float4*)(w_coef + k1 * LSD);
        const float4* w2 = (const float4*)(w_coef + k2 * LSD);
        const float4* w3 = (const float4*)(w_coef + k3 * LSD);
        float a0 = b_coef[k0], a1 = b_coef[k1], a2 = b_coef[k2], a3 = b_coef[k3];
        #pragma unroll 6
        for (int d = 0; d < LSD / 4; ++d) {
            float4 p = pmv[d];
            float4 u0 = w0[d], u1 = w1[d], u2 = w2[d], u3 = w3[d];
            a0 = fmaf(p.x, u0.x, a0); a0 = fmaf(p.y, u0.y, a0);
            a0 = fmaf(p.z, u0.z, a0); a0 = fmaf(p.w, u0.w, a0);
            a1 = fmaf(p.x, u1.x, a1); a1 = fmaf(p.y, u1.y, a1);
            a1 = fmaf(p.z, u1.z, a1); a1 = fmaf(p.w, u1.w, a1);
            a2 = fmaf(p.x, u2.x, a2); a2 = fmaf(p.y, u2.y, a2);
            a2 = fmaf(p.z, u2.z, a2); a2 = fmaf(p.w, u2.w, a2);
            a3 = fmaf(p.x, u3.x, a3); a3 = fmaf(p.y, u3.y, a3);
            a3 = fmaf(p.z, u3.z, a3); a3 = fmaf(p.w, u3.w, a3);
        }
        coef_s[k0 * 64 + lane] = a0;
        coef_s[k1 * 64 + lane] = a1;
        coef_s[k2 * 64 + lane] = a2;
        if (wv < 3) coef_s[k3 * 64 + lane] = a3;
    }
    __syncthreads();   // barrier 1: all logits visible

    // ---------------- phase 1b: staging (issue loads early) ---------------
    float* vsb    = ovl;                 // [v][jj][b], stride 65
    float* pack_s = ovl + VS_FLOATS;     // linear idx == LDS addr (stride-1)

    for (int idx = tid; idx < 5 * 64 * NJJ; idx += 256) {   // 5120: 20 iters
        int jj  = idx & 15;                                 // pow2 decode
        int blc = (idx >> 4) & 63;
        int v   = idx >> 10;
        int j   = i0 - BW + jj;
        int bb  = b0 + blc;
        float val = 0.0f;
        if (j >= 0 && j < LOD) {
            if (v == 0)      val = pm[bb * LSD + j];
            else if (v == 1) val = pm[bb * LSD + LOD + j];
            else if (v == 2) val = cu[bb * LOD + j];
            else if (v == 3) val = cl[bb * LOD + j];
            else             val = cs[bb * LOD + j];
        }
        vsb[v * VSV + jj * VSJ + blc] = val;
    }
    for (int idx = tid; idx < PACK_FLOATS; idx += 256) {    // 4200: ~16.4 iters
        int m  = idx & 3;
        int q  = idx >> 2;
        int jo = q % 7;
        int q2 = q / 7;
        int k  = q2 % NB;
        int ri = q2 / NB;
        int i  = i0 + ri;
        int j  = i - BW + jo;
        const float* tmm = (m == 0) ? tm11 : (m == 1) ? tm12 : (m == 2) ? tm21 : tm22;
        float val = (j >= 0 && j < LOD) ? tmm[k * (LOD * LOD) + i * LOD + j] : 0.0f;
        pack_s[idx] = val;              // write addr == idx: zero conflicts
    }

    // ---------------- phase 1c: softmax (wave 0) --------------------------
    if (tid < 64) {
        float v[NB];
        float mx = -1e30f;
        #pragma unroll
        for (int k = 0; k < NB; ++k) { v[k] = coef_s[k * 64 + tid]; mx = fmaxf(mx, v[k]); }
        float sm = 0.0f;
        #pragma unroll
        for (int k = 0; k < NB; ++k) { v[k] = __expf(v[k] - mx); sm += v[k]; }
        float inv = 1.0f / sm;
        #pragma unroll
        for (int k = 0; k < NB; ++k) coef_s[k * 64 + tid] = v[k] * inv;
    }

    // ---------------- phase 1d: control rows (6 scalars, own rows only) ---
    // Wave w rows: w0:{0,1,2} w1:{3,4,5} w2:{6,7,(7)} w3:{8,9,(9)} (clamped).
    const int lim   = (wv < 2) ? 2 : 1;
    const int rbase = (wv < 2) ? wv * 3 : 6 + (wv - 2) * 2;
    int rcl[3];                          // static-index use only
    rcl[0] = rbase; rcl[1] = rbase + 1; rcl[2] = rbase + lim;

    float ctl[6];
    #pragma unroll
    for (int rr = 0; rr < 3; ++rr) {
        ctl[rr]     = b_c2[i0 + rcl[rr]];
        ctl[3 + rr] = b_c2[LOD + i0 + rcl[rr]];
    }
    {
        float av[AD];
        const float2* a2p = (const float2*)(action + (size_t)(b0 + lane) * AD);
        #pragma unroll
        for (int z = 0; z < 5; ++z) { float2 t2 = a2p[z]; av[2 * z] = t2.x; av[2 * z + 1] = t2.y; }
        #pragma unroll 4
        for (int h = 0; h < H; ++h) {
            float hv = b_c1[h];
            #pragma unroll
            for (int a = 0; a < AD; ++a) hv = fmaf(av[a], w_c1[h * AD + a], hv);
            hv = fmaxf(hv, 0.0f);
            #pragma unroll
            for (int rr = 0; rr < 3; ++rr) {
                ctl[rr]     = fmaf(hv, w_c2[(i0 + rcl[rr]) * H + h], ctl[rr]);
                ctl[3 + rr] = fmaf(hv, w_c2[(LOD + i0 + rcl[rr]) * H + h], ctl[3 + rr]);
            }
        }
    }
    __syncthreads();   // barrier 2: coef final, vs/pack staged

    // ---------------- phase 2: mixing + banded products -------------------
    float cf[NB];
    #pragma unroll
    for (int k = 0; k < NB; ++k) cf[k] = coef_s[k * 64 + lane];

    float onm[3], onl[3], ouv[3], olv[3], osv[3];
    #pragma unroll
    for (int rr = 0; rr < 3; ++rr) {
        const int riu = rcl[rr];          // wave-uniform (clamped dup for w2/w3)
        const int iu  = i0 + riu;

        float t[28];
        #pragma unroll
        for (int z = 0; z < 28; ++z) t[z] = 0.0f;
        const float4* tp = (const float4*)pack_s + riu * (NB * 7);
        #pragma unroll
        for (int k = 0; k < NB; ++k) {
            float c = cf[k];
            #pragma unroll
            for (int jo = 0; jo < 7; ++jo) {
                float4 tv = tp[k * 7 + jo];   // uniform addr -> LDS broadcast
                t[jo * 4 + 0] = fmaf(c, tv.x, t[jo * 4 + 0]);
                t[jo * 4 + 1] = fmaf(c, tv.y, t[jo * 4 + 1]);
                t[jo * 4 + 2] = fmaf(c, tv.z, t[jo * 4 + 2]);
                t[jo * 4 + 3] = fmaf(c, tv.w, t[jo * 4 + 3]);
            }
        }
        t[3 * 4 + 0] += 1.0f;    // + eye on t11 at j == i
        t[3 * 4 + 3] += 1.0f;    // + eye on t22 at j == i

        float nmu = 0.f, nml = 0.f, ncuv = 0.f, nclv = 0.f, ncsv = 0.f;
        #pragma unroll
        for (int jo = 0; jo < 7; ++jo) {
            const int jj = riu + jo;      // 0..15, in-plane (OOB j zero-filled)
            float m_ = vsb[0 * VSV + jj * VSJ + lane];
            float n_ = vsb[1 * VSV + jj * VSJ + lane];
            float u_ = vsb[2 * VSV + jj * VSJ + lane];
            float l_ = vsb[3 * VSV + jj * VSJ + lane];
            float s_ = vsb[4 * VSV + jj * VSJ + lane];
            float A = t[jo * 4 + 0], Bv = t[jo * 4 + 1];
            float C = t[jo * 4 + 2], D  = t[jo * 4 + 3];
            nmu = fmaf(A, m_, nmu);  nmu = fmaf(Bv, n_, nmu);
            nml = fmaf(C, m_, nml);  nml = fmaf(D, n_, nml);
            float e1 = fmaf(Bv, s_, A * u_);
            float e2 = fmaf(Bv, l_, A * s_);
            float f1 = fmaf(D, s_, C * u_);
            float f2 = fmaf(D, l_, C * s_);
            ncuv = fmaf(A, e1, ncuv);  ncuv = fmaf(Bv, e2, ncuv);
            nclv = fmaf(C, f1, nclv);  nclv = fmaf(D, f2, nclv);
            ncsv = fmaf(C, e1, ncsv);  ncsv = fmaf(D, e2, ncsv);
        }
        ncuv += elup1f(log_noise[iu]);
        nclv += elup1f(log_noise[LOD + iu]);
        nmu  += ctl[rr];
        nml  += ctl[3 + rr];
        onm[rr] = nmu; onl[rr] = nml; ouv[rr] = ncuv; olv[rr] = nclv; osv[rr] = ncsv;
    }
    __syncthreads();   // barrier 3: all reads of pack_s done -> overlay ost

    float* ost = ovl + VS_FLOATS;        // [t5][rq][b], stride 65
    #pragma unroll
    for (int rr = 0; rr < 3; ++rr) {
        const int ri = rcl[rr];          // dup rows: identical double-write, benign
        ost[0 * OST_PLANE + ri * 65 + lane] = onm[rr];
        ost[1 * OST_PLANE + ri * 65 + lane] = onl[rr];
        ost[2 * OST_PLANE + ri * 65 + lane] = ouv[rr];
        ost[3 * OST_PLANE + ri * 65 + lane] = olv[rr];
        ost[4 * OST_PLANE + ri * 65 + lane] = osv[rr];
    }
    __syncthreads();   // barrier 4

    // coalesced flush: pow2-padded decode, 40 B contiguous runs per (t5,b)
    for (int idx = tid; idx < 5 * 64 * 16; idx += 256) {    // 5120: 20 iters
        int rq  = idx & 15;
        if (rq >= RG_ROWS) continue;
        int blc = (idx >> 4) & 63;
        int t5  = idx >> 10;
        int bb  = b0 + blc;
        float v = ost[t5 * OST_PLANE + rq * 65 + blc];
        float* bp;
        if (t5 == 0)      bp = out + bb * LSD + i0;
        else if (t5 == 1) bp = out + bb * LSD + LOD + i0;
        else if (t5 == 2) bp = out + NM_SZ + bb * LOD + i0;
        else if (t5 == 3) bp = out + NM_SZ + NC_SZ + bb * LOD + i0;
        else              bp = out + NM_SZ + 2 * NC_SZ + bb * LOD + i0;
        bp[rq] = v;
    }
}

extern "C" void kernel_launch(void* const* d_in, const int* in_sizes, int n_in,
                              void* d_out, int out_size, void* d_ws, size_t ws_size,
                              hipStream_t stream) {
    (void)in_sizes; (void)n_in; (void)out_size; (void)d_ws; (void)ws_size;
    const float* pm        = (const float*)d_in[0];
    const float* cu        = (const float*)d_in[1];
    const float* cl        = (const float*)d_in[2];
    const float* cs        = (const float*)d_in[3];
    const float* action    = (const float*)d_in[4];
    const float* tm11      = (const float*)d_in[5];
    const float* tm12      = (const float*)d_in[6];
    const float* tm21      = (const float*)d_in[7];
    const float* tm22      = (const float*)d_in[8];
    const float* log_noise = (const float*)d_in[9];
    const float* w_coef    = (const float*)d_in[10];
    const float* b_coef    = (const float*)d_in[11];
    const float* w_c1      = (const float*)d_in[12];
    const float* b_c1      = (const float*)d_in[13];
    const float* w_c2      = (const float*)d_in[14];
    const float* b_c2      = (const float*)d_in[15];

    hipLaunchKernelGGL(k_fused, dim3(768), dim3(256), 0, stream,
                       pm, cu, cl, cs, action, tm11, tm12, tm21, tm22,
                       log_noise, w_coef, b_coef, w_c1, b_c1, w_c2, b_c2,
                       (float*)d_out);
}

// Round 5
// 119.154 us; speedup vs baseline: 3.7718x; 1.1027x over previous
//
#include <hip/hip_runtime.h>
#include <math.h>

// Problem constants
#define BATCH 8192
#define LOD 60
#define LSD 120
#define AD 10
#define NB 15
#define BW 3
#define H 60

// Output layout (floats)
#define NM_SZ (BATCH * LSD)   // next_mean 983040
#define NC_SZ (BATCH * LOD)   // 491520 each for ncu/ncl/ncs

// Geometry: 128 batch-groups (64 batches) x 8 row-groups (8 rows) = 1024 blocks.
// 4 blocks/CU (34.2 KB LDS) -> 16 waves/CU, one clean round.
// Each wave owns exactly 2 rows: {2wv, 2wv+1}. rg 7 rows 60..63 are computed
// as guarded garbage and skipped at flush.
#define RGS 8
#define RG_ROWS 8
#define NJJ 16                        // 8 + 2*BW = 14, padded to pow2
#define VSJ 65
#define VSV (NJJ * VSJ)               // 1040 floats per staged plane
#define PACK_FLOATS (RG_ROWS * NB * 28)   // 3360
#define VS_OFF PACK_FLOATS                // vs @ 3360
#define VS_FLOATS (5 * VSV)               // 5200
#define OVL_FLOATS (VS_OFF + VS_FLOATS)   // 8560 floats = 34.24 KB
// phase-1 overlay (inside the vs region, untouched until after bar2):
#define COEF_OFF VS_OFF                   // [k][b] 15*64 = 960
#define HID_OFF (VS_OFF + NB * 64)        // [h][b] stride 65, 60*65 = 3900
#define OST_PLANE (RG_ROWS * 65)          // 520; ost (2600) overlays pack (3360)

__device__ __forceinline__ float elup1f(float x) {
    return x < 0.0f ? __expf(x) : x + 1.0f;
}

__global__ __launch_bounds__(256, 4) void k_fused(
    const float* __restrict__ pm, const float* __restrict__ cu,
    const float* __restrict__ cl, const float* __restrict__ cs,
    const float* __restrict__ action,
    const float* __restrict__ tm11, const float* __restrict__ tm12,
    const float* __restrict__ tm21, const float* __restrict__ tm22,
    const float* __restrict__ log_noise,
    const float* __restrict__ w_coef, const float* __restrict__ b_coef,
    const float* __restrict__ w_c1, const float* __restrict__ b_c1,
    const float* __restrict__ w_c2, const float* __restrict__ b_c2,
    float* __restrict__ out)
{
    __shared__ __align__(16) float ovl[OVL_FLOATS];  // 34.24 KB total

    const int tid  = threadIdx.x;
    const int lane = tid & 63;
    const int wv   = __builtin_amdgcn_readfirstlane(tid >> 6);

    // XCD-grouped swizzle: the 8 rg-blocks of one bg share one XCD's L2.
    const int bid  = blockIdx.x;            // 1024 = 8 XCDs * 128
    const int xcd  = bid & 7;
    const int slot = bid >> 3;              // 0..127
    const int bg   = xcd * 16 + (slot >> 3);
    const int rg   = slot & 7;
    const int b0   = bg * 64;
    const int i0   = rg * RG_ROWS;

    float* pack_s = ovl;                 // @0
    float* vsb    = ovl + VS_OFF;
    float* coefL  = ovl + COEF_OFF;      // phase-1 overlay
    float* hid_s  = ovl + HID_OFF;       // phase-1 overlay

    // ---------------- phase A: logits + shared hidden layer ----------------
    {
        const int k0 = wv, k1 = wv + 4, k2 = wv + 8;
        const int k3 = (wv < 3) ? wv + 12 : 14;     // wave 3: dummy stream
        const float4* pmv = (const float4*)(pm + (size_t)(b0 + lane) * LSD);
        const float4* w0 = (const float4*)(w_coef + k0 * LSD);
        const float4* w1 = (const float4*)(w_coef + k1 * LSD);
        const float4* w2 = (const float4*)(w_coef + k2 * LSD);
        const float4* w3 = (const float4*)(w_coef + k3 * LSD);
        float a0 = b_coef[k0], a1 = b_coef[k1], a2 = b_coef[k2], a3 = b_coef[k3];
        #pragma unroll 6
        for (int d = 0; d < LSD / 4; ++d) {
            float4 p = pmv[d];
            float4 u0 = w0[d], u1 = w1[d], u2 = w2[d], u3 = w3[d];
            a0 = fmaf(p.x, u0.x, a0); a0 = fmaf(p.y, u0.y, a0);
            a0 = fmaf(p.z, u0.z, a0); a0 = fmaf(p.w, u0.w, a0);
            a1 = fmaf(p.x, u1.x, a1); a1 = fmaf(p.y, u1.y, a1);
            a1 = fmaf(p.z, u1.z, a1); a1 = fmaf(p.w, u1.w, a1);
            a2 = fmaf(p.x, u2.x, a2); a2 = fmaf(p.y, u2.y, a2);
            a2 = fmaf(p.z, u2.z, a2); a2 = fmaf(p.w, u2.w, a2);
            a3 = fmaf(p.x, u3.x, a3); a3 = fmaf(p.y, u3.y, a3);
            a3 = fmaf(p.z, u3.z, a3); a3 = fmaf(p.w, u3.w, a3);
        }
        coefL[k0 * 64 + lane] = a0;
        coefL[k1 * 64 + lane] = a1;
        coefL[k2 * 64 + lane] = a2;
        if (wv < 3) coefL[k3 * 64 + lane] = a3;
    }
    {   // hidden layer, shared: wave wv owns h in [15wv, 15wv+15)
        float av[AD];
        const float2* a2p = (const float2*)(action + (size_t)(b0 + lane) * AD);
        #pragma unroll
        for (int z = 0; z < 5; ++z) { float2 t2 = a2p[z]; av[2 * z] = t2.x; av[2 * z + 1] = t2.y; }
        #pragma unroll
        for (int q = 0; q < 15; ++q) {
            int h = wv * 15 + q;
            float acc = b_c1[h];
            #pragma unroll
            for (int a = 0; a < AD; ++a)
                acc = fmaf(av[a], w_c1[h * AD + a], acc);   // uniform -> s_load
            hid_s[h * 65 + lane] = fmaxf(acc, 0.0f);
        }
    }
    __syncthreads();   // bar1: logits + hidden visible

    // ---------------- phase B ----------------
    // (a) T14: issue vs global loads to registers EARLY; latency hides under
    //     pack staging + softmax + control-dot. Per-thread jj/j are fixed.
    float vr[20];
    {
        const int jj  = tid & 15;
        const int j   = i0 - BW + jj;
        const bool jok = (j >= 0) && (j < LOD);
        #pragma unroll
        for (int z = 0; z < 20; ++z) {
            const int idx = z * 256 + tid;
            const int blc = (idx >> 4) & 63;
            const int bb  = b0 + blc;
            float val = 0.0f;
            if (jok) {
                const int v = z >> 2;                  // compile-time per z
                if (v == 0)      val = pm[bb * LSD + j];
                else if (v == 1) val = pm[bb * LSD + LOD + j];
                else if (v == 2) val = cu[bb * LOD + j];
                else if (v == 3) val = cl[bb * LOD + j];
                else             val = cs[bb * LOD + j];
            }
            vr[z] = val;
        }
    }

    // (b) pack staging direct to LDS @0 (no overlap with coef/hid @3360+)
    for (int idx = tid; idx < PACK_FLOATS; idx += 256) {
        int m  = idx & 3;
        int q  = idx >> 2;
        int jo = q % 7;
        int q2 = q / 7;
        int k  = q2 % NB;
        int ri = q2 / NB;
        int i  = i0 + ri;
        int j  = i - BW + jo;
        const float* tmm = (m == 0) ? tm11 : (m == 1) ? tm12 : (m == 2) ? tm21 : tm22;
        float val = (i < LOD && j >= 0 && j < LOD) ? tmm[k * (LOD * LOD) + i * LOD + j] : 0.0f;
        pack_s[idx] = val;               // write addr == idx: zero conflicts
    }

    // (c) all-lane register softmax (no serialization, no write-back)
    float cf[NB];
    {
        float mx = -1e30f;
        #pragma unroll
        for (int k = 0; k < NB; ++k) { cf[k] = coefL[k * 64 + lane]; mx = fmaxf(mx, cf[k]); }
        float sm = 0.0f;
        #pragma unroll
        for (int k = 0; k < NB; ++k) { cf[k] = __expf(cf[k] - mx); sm += cf[k]; }
        float inv = 1.0f / sm;
        #pragma unroll
        for (int k = 0; k < NB; ++k) cf[k] *= inv;
    }

    // (d) control out-dot for this wave's two rows (from shared hidden)
    const int r0g = i0 + 2 * wv;
    const int c0  = (r0g < LOD) ? r0g : LOD - 1;        // rg7/wv3 clamp (reads only)
    const int c1  = (r0g + 1 < LOD) ? r0g + 1 : LOD - 1;
    float ctl0 = b_c2[c0], ctl1 = b_c2[c1];
    float ctl2 = b_c2[LOD + c0], ctl3 = b_c2[LOD + c1];
    #pragma unroll 4
    for (int h = 0; h < H; ++h) {
        float hv = hid_s[h * 65 + lane];                // lane-stride-1
        ctl0 = fmaf(hv, w_c2[c0 * H + h], ctl0);        // uniform -> s_load
        ctl1 = fmaf(hv, w_c2[c1 * H + h], ctl1);
        ctl2 = fmaf(hv, w_c2[(LOD + c0) * H + h], ctl2);
        ctl3 = fmaf(hv, w_c2[(LOD + c1) * H + h], ctl3);
    }
    __syncthreads();   // bar2: all reads of coef/hid done

    // ---------------- phase C: vs LDS writes (data already in regs) --------
    {
        const int jj = tid & 15;
        #pragma unroll
        for (int z = 0; z < 20; ++z) {
            const int idx = z * 256 + tid;
            const int blc = (idx >> 4) & 63;
            vsb[(z >> 2) * VSV + jj * VSJ + blc] = vr[z];   // 2-way alias: free
        }
    }
    __syncthreads();   // bar3: vs + pack staged

    // ---------------- phase D: mixing + banded products --------------------
    float onm[2], onl[2], ouv[2], olv[2], osv[2];
    #pragma unroll
    for (int rr = 0; rr < 2; ++rr) {
        const int riu = 2 * wv + rr;                    // wave-uniform, no dups
        const int iu  = i0 + riu;
        const int iuc = (iu < LOD) ? iu : LOD - 1;

        float t[28];
        #pragma unroll
        for (int z = 0; z < 28; ++z) t[z] = 0.0f;
        const float4* tp = (const float4*)pack_s + riu * (NB * 7);
        #pragma unroll
        for (int k = 0; k < NB; ++k) {
            float c = cf[k];
            #pragma unroll
            for (int jo = 0; jo < 7; ++jo) {
                float4 tv = tp[k * 7 + jo];             // uniform -> broadcast
                t[jo * 4 + 0] = fmaf(c, tv.x, t[jo * 4 + 0]);
                t[jo * 4 + 1] = fmaf(c, tv.y, t[jo * 4 + 1]);
                t[jo * 4 + 2] = fmaf(c, tv.z, t[jo * 4 + 2]);
                t[jo * 4 + 3] = fmaf(c, tv.w, t[jo * 4 + 3]);
            }
        }
        t[3 * 4 + 0] += 1.0f;    // + eye on t11 at j == i
        t[3 * 4 + 3] += 1.0f;    // + eye on t22 at j == i

        float nmu = 0.f, nml = 0.f, ncuv = 0.f, nclv = 0.f, ncsv = 0.f;
        #pragma unroll
        for (int jo = 0; jo < 7; ++jo) {
            const int jj = riu + jo;                    // 0..13 < NJJ
            float m_ = vsb[0 * VSV + jj * VSJ + lane];
            float n_ = vsb[1 * VSV + jj * VSJ + lane];
            float u_ = vsb[2 * VSV + jj * VSJ + lane];
            float l_ = vsb[3 * VSV + jj * VSJ + lane];
            float s_ = vsb[4 * VSV + jj * VSJ + lane];
            float A = t[jo * 4 + 0], Bv = t[jo * 4 + 1];
            float C = t[jo * 4 + 2], D  = t[jo * 4 + 3];
            nmu = fmaf(A, m_, nmu);  nmu = fmaf(Bv, n_, nmu);
            nml = fmaf(C, m_, nml);  nml = fmaf(D, n_, nml);
            float e1 = fmaf(Bv, s_, A * u_);
            float e2 = fmaf(Bv, l_, A * s_);
            float f1 = fmaf(D, s_, C * u_);
            float f2 = fmaf(D, l_, C * s_);
            ncuv = fmaf(A, e1, ncuv);  ncuv = fmaf(Bv, e2, ncuv);
            nclv = fmaf(C, f1, nclv);  nclv = fmaf(D, f2, nclv);
            ncsv = fmaf(C, e1, ncsv);  ncsv = fmaf(D, e2, ncsv);
        }
        ncuv += elup1f(log_noise[iuc]);
        nclv += elup1f(log_noise[LOD + iuc]);
        nmu  += (rr == 0) ? ctl0 : ctl1;
        nml  += (rr == 0) ? ctl2 : ctl3;
        onm[rr] = nmu; onl[rr] = nml; ouv[rr] = ncuv; olv[rr] = nclv; osv[rr] = ncsv;
    }
    __syncthreads();   // bar4: all reads of pack_s done -> overlay ost

    // ---------------- phase E: ost staging + float4 flush -------------------
    float* ost = ovl;                    // [t5][ri][b], overlays pack
    #pragma unroll
    for (int rr = 0; rr < 2; ++rr) {
        const int ri = 2 * wv + rr;
        ost[0 * OST_PLANE + ri * 65 + lane] = onm[rr];
        ost[1 * OST_PLANE + ri * 65 + lane] = onl[rr];
        ost[2 * OST_PLANE + ri * 65 + lane] = ouv[rr];
        ost[3 * OST_PLANE + ri * 65 + lane] = olv[rr];
        ost[4 * OST_PLANE + ri * 65 + lane] = osv[rr];
    }
    __syncthreads();   // bar5

    // float4 flush: 640 stores total, 16B-aligned (i0 % 8 == 0)
    for (int idx = tid; idx < 5 * 64 * 2; idx += 256) {
        int q   = idx & 1;
        int blc = (idx >> 1) & 63;
        int t5  = idx >> 7;
        if (i0 + q * 4 + 3 >= LOD) continue;     // only rg7, q=1
        int bb = b0 + blc;
        int ro = q * 4;
        float4 v;
        v.x = ost[t5 * OST_PLANE + (ro + 0) * 65 + blc];
        v.y = ost[t5 * OST_PLANE + (ro + 1) * 65 + blc];
        v.z = ost[t5 * OST_PLANE + (ro + 2) * 65 + blc];
        v.w = ost[t5 * OST_PLANE + (ro + 3) * 65 + blc];
        float* bp;
        if (t5 == 0)      bp = out + bb * LSD + i0;
        else if (t5 == 1) bp = out + bb * LSD + LOD + i0;
        else if (t5 == 2) bp = out + NM_SZ + bb * LOD + i0;
        else if (t5 == 3) bp = out + NM_SZ + NC_SZ + bb * LOD + i0;
        else              bp = out + NM_SZ + 2 * NC_SZ + bb * LOD + i0;
        *(float4*)(bp + ro) = v;
    }
}

extern "C" void kernel_launch(void* const* d_in, const int* in_sizes, int n_in,
                              void* d_out, int out_size, void* d_ws, size_t ws_size,
                              hipStream_t stream) {
    (void)in_sizes; (void)n_in; (void)out_size; (void)d_ws; (void)ws_size;
    const float* pm        = (const float*)d_in[0];
    const float* cu        = (const float*)d_in[1];
    const float* cl        = (const float*)d_in[2];
    const float* cs        = (const float*)d_in[3];
    const float* action    = (const float*)d_in[4];
    const float* tm11      = (const float*)d_in[5];
    const float* tm12      = (const float*)d_in[6];
    const float* tm21      = (const float*)d_in[7];
    const float* tm22      = (const float*)d_in[8];
    const float* log_noise = (const float*)d_in[9];
    const float* w_coef    = (const float*)d_in[10];
    const float* b_coef    = (const float*)d_in[11];
    const float* w_c1      = (const float*)d_in[12];
    const float* b_c1      = (const float*)d_in[13];
    const float* w_c2      = (const float*)d_in[14];
    const float* b_c2      = (const float*)d_in[15];

    hipLaunchKernelGGL(k_fused, dim3(1024), dim3(256), 0, stream,
                       pm, cu, cl, cs, action, tm11, tm12, tm21, tm22,
                       log_noise, w_coef, b_coef, w_c1, b_c1, w_c2, b_c2,
                       (float*)d_out);
}

// Round 6
// 117.658 us; speedup vs baseline: 3.8197x; 1.0127x over previous
//
#include <hip/hip_runtime.h>
#include <math.h>

// Problem constants
#define BATCH 8192
#define LOD 60
#define LSD 120
#define AD 10
#define NB 15
#define BW 3
#define H 60

// Output layout (floats)
#define NM_SZ (BATCH * LSD)   // next_mean 983040
#define NC_SZ (BATCH * LOD)   // 491520 each for ncu/ncl/ncs

// Geometry: 128 batch-groups (64 batches) x 8 row-groups (8 rows) = 1024 blocks.
// 4 blocks/CU (34.2 KB LDS) -> 16 waves/CU, one clean round.
#define RGS 8
#define RG_ROWS 8
#define NJJ 16                        // 8 + 2*BW = 14, padded to pow2
#define VSJ 65
#define VSV (NJJ * VSJ)               // 1040 floats per staged plane
#define PACK_FLOATS (RG_ROWS * NB * 28)   // 3360
#define VS_OFF PACK_FLOATS                // vs @ 3360
#define VS_FLOATS (5 * VSV)               // 5200
#define OVL_FLOATS (VS_OFF + VS_FLOATS)   // 8560 floats = 34.24 KB
#define COEF_OFF VS_OFF                   // [k][b] 15*64 = 960
#define HID_OFF (VS_OFF + NB * 64)        // [h][b] stride 65, 60*65 = 3900
#define OST_PLANE (RG_ROWS * 65)          // 520; ost (2600) overlays pack (3360)

typedef float v2f __attribute__((ext_vector_type(2)));
#define FMA2(a, b, c) __builtin_elementwise_fma((a), (b), (c))

__device__ __forceinline__ float elup1f(float x) {
    return x < 0.0f ? __expf(x) : x + 1.0f;
}

__global__ __launch_bounds__(256, 4) void k_fused(
    const float* __restrict__ pm, const float* __restrict__ cu,
    const float* __restrict__ cl, const float* __restrict__ cs,
    const float* __restrict__ action,
    const float* __restrict__ tm11, const float* __restrict__ tm12,
    const float* __restrict__ tm21, const float* __restrict__ tm22,
    const float* __restrict__ log_noise,
    const float* __restrict__ w_coef, const float* __restrict__ b_coef,
    const float* __restrict__ w_c1, const float* __restrict__ b_c1,
    const float* __restrict__ w_c2, const float* __restrict__ b_c2,
    float* __restrict__ out)
{
    __shared__ __align__(16) float ovl[OVL_FLOATS];  // 34.24 KB total

    const int tid  = threadIdx.x;
    const int lane = tid & 63;
    const int wv   = __builtin_amdgcn_readfirstlane(tid >> 6);

    // XCD-grouped swizzle: the 8 rg-blocks of one bg share one XCD's L2.
    const int bid  = blockIdx.x;            // 1024 = 8 XCDs * 128
    const int xcd  = bid & 7;
    const int slot = bid >> 3;              // 0..127
    const int bg   = xcd * 16 + (slot >> 3);
    const int rg   = slot & 7;
    const int b0   = bg * 64;
    const int i0   = rg * RG_ROWS;

    float* pack_s = ovl;                 // @0
    float* vsb    = ovl + VS_OFF;
    float* coefL  = ovl + COEF_OFF;      // phase-1 overlay
    float* hid_s  = ovl + HID_OFF;       // phase-1 overlay

    // ---------------- phase A: logits + shared hidden layer ----------------
    {
        const int k0 = wv, k1 = wv + 4, k2 = wv + 8;
        const int k3 = (wv < 3) ? wv + 12 : 14;     // wave 3: dummy stream
        const float4* pmv = (const float4*)(pm + (size_t)(b0 + lane) * LSD);
        const float4* w0 = (const float4*)(w_coef + k0 * LSD);
        const float4* w1 = (const float4*)(w_coef + k1 * LSD);
        const float4* w2 = (const float4*)(w_coef + k2 * LSD);
        const float4* w3 = (const float4*)(w_coef + k3 * LSD);
        v2f a0 = {0.f, 0.f}, a1 = {0.f, 0.f}, a2 = {0.f, 0.f}, a3 = {0.f, 0.f};
        #pragma unroll 6
        for (int d = 0; d < LSD / 4; ++d) {
            float4 p = pmv[d];
            v2f plo = {p.x, p.y}, phi = {p.z, p.w};
            float4 u0 = w0[d], u1 = w1[d], u2 = w2[d], u3 = w3[d];
            a0 = FMA2(plo, ((v2f){u0.x, u0.y}), a0);
            a0 = FMA2(phi, ((v2f){u0.z, u0.w}), a0);
            a1 = FMA2(plo, ((v2f){u1.x, u1.y}), a1);
            a1 = FMA2(phi, ((v2f){u1.z, u1.w}), a1);
            a2 = FMA2(plo, ((v2f){u2.x, u2.y}), a2);
            a2 = FMA2(phi, ((v2f){u2.z, u2.w}), a2);
            a3 = FMA2(plo, ((v2f){u3.x, u3.y}), a3);
            a3 = FMA2(phi, ((v2f){u3.z, u3.w}), a3);
        }
        coefL[k0 * 64 + lane] = a0.x + a0.y + b_coef[k0];
        coefL[k1 * 64 + lane] = a1.x + a1.y + b_coef[k1];
        coefL[k2 * 64 + lane] = a2.x + a2.y + b_coef[k2];
        if (wv < 3) coefL[k3 * 64 + lane] = a3.x + a3.y + b_coef[k3];
    }
    {   // hidden layer, shared: wave wv owns h in [15wv, 15wv+15)
        v2f av2[5];
        const float2* a2p = (const float2*)(action + (size_t)(b0 + lane) * AD);
        #pragma unroll
        for (int z = 0; z < 5; ++z) { float2 t2 = a2p[z]; av2[z] = (v2f){t2.x, t2.y}; }
        #pragma unroll
        for (int q = 0; q < 15; ++q) {
            int h = wv * 15 + q;
            v2f acc2 = {0.f, 0.f};
            #pragma unroll
            for (int z = 0; z < 5; ++z)
                acc2 = FMA2(av2[z], *(const v2f*)(w_c1 + h * AD + 2 * z), acc2);  // uniform 8B s_load
            float acc = acc2.x + acc2.y + b_c1[h];
            hid_s[h * 65 + lane] = fmaxf(acc, 0.0f);
        }
    }
    __syncthreads();   // bar1: logits + hidden visible

    // ---------------- phase B ----------------
    // (a) T14: issue vs global loads to registers EARLY; latency hides under
    //     pack staging + softmax + control-dot.
    float vr[20];
    {
        const int jj  = tid & 15;
        const int j   = i0 - BW + jj;
        const bool jok = (j >= 0) && (j < LOD);
        #pragma unroll
        for (int z = 0; z < 20; ++z) {
            const int idx = z * 256 + tid;
            const int blc = (idx >> 4) & 63;
            const int bb  = b0 + blc;
            float val = 0.0f;
            if (jok) {
                const int v = z >> 2;                  // compile-time per z
                if (v == 0)      val = pm[bb * LSD + j];
                else if (v == 1) val = pm[bb * LSD + LOD + j];
                else if (v == 2) val = cu[bb * LOD + j];
                else if (v == 3) val = cl[bb * LOD + j];
                else             val = cs[bb * LOD + j];
            }
            vr[z] = val;
        }
    }

    // (b) pack staging direct to LDS @0 (no overlap with coef/hid @3360+)
    for (int idx = tid; idx < PACK_FLOATS; idx += 256) {
        int m  = idx & 3;
        int q  = idx >> 2;
        int jo = q % 7;
        int q2 = q / 7;
        int k  = q2 % NB;
        int ri = q2 / NB;
        int i  = i0 + ri;
        int j  = i - BW + jo;
        const float* tmm = (m == 0) ? tm11 : (m == 1) ? tm12 : (m == 2) ? tm21 : tm22;
        float val = (i < LOD && j >= 0 && j < LOD) ? tmm[k * (LOD * LOD) + i * LOD + j] : 0.0f;
        pack_s[idx] = val;               // write addr == idx: zero conflicts
    }

    // (c) all-lane register softmax
    float cf[NB];
    {
        float mx = -1e30f;
        #pragma unroll
        for (int k = 0; k < NB; ++k) { cf[k] = coefL[k * 64 + lane]; mx = fmaxf(mx, cf[k]); }
        float sm = 0.0f;
        #pragma unroll
        for (int k = 0; k < NB; ++k) { cf[k] = __expf(cf[k] - mx); sm += cf[k]; }
        float inv = 1.0f / sm;
        #pragma unroll
        for (int k = 0; k < NB; ++k) cf[k] *= inv;
    }

    // (d) control out-dot for this wave's two rows (from shared hidden)
    const int r0g = i0 + 2 * wv;
    const int c0  = (r0g < LOD) ? r0g : LOD - 1;        // rg7/wv3 clamp (reads only)
    const int c1  = (r0g + 1 < LOD) ? r0g + 1 : LOD - 1;
    float ctl0 = b_c2[c0], ctl1 = b_c2[c1];
    float ctl2 = b_c2[LOD + c0], ctl3 = b_c2[LOD + c1];
    #pragma unroll 4
    for (int h = 0; h < H; ++h) {
        float hv = hid_s[h * 65 + lane];                // lane-stride-1
        ctl0 = fmaf(hv, w_c2[c0 * H + h], ctl0);        // uniform -> s_load
        ctl1 = fmaf(hv, w_c2[c1 * H + h], ctl1);
        ctl2 = fmaf(hv, w_c2[(LOD + c0) * H + h], ctl2);
        ctl3 = fmaf(hv, w_c2[(LOD + c1) * H + h], ctl3);
    }
    __syncthreads();   // bar2: all reads of coef/hid done

    // ---------------- phase C: vs LDS writes (data already in regs) --------
    {
        const int jj = tid & 15;
        #pragma unroll
        for (int z = 0; z < 20; ++z) {
            const int idx = z * 256 + tid;
            const int blc = (idx >> 4) & 63;
            vsb[(z >> 2) * VSV + jj * VSJ + blc] = vr[z];   // 2-way alias: free
        }
    }
    __syncthreads();   // bar3: vs + pack staged

    // ---------------- phase D: mixing + banded products (packed f32) ------
    float onm[2], onl[2], ouv[2], olv[2], osv[2];
    #pragma unroll
    for (int rr = 0; rr < 2; ++rr) {
        const int riu = 2 * wv + rr;                    // wave-uniform
        const int iu  = i0 + riu;
        const int iuc = (iu < LOD) ? iu : LOD - 1;

        // t2[2*jo]   = {A,  Bv}  (m=0,1);  t2[2*jo+1] = {C, D}  (m=2,3)
        v2f t2[14];
        #pragma unroll
        for (int z = 0; z < 14; ++z) t2[z] = (v2f){0.f, 0.f};
        const float4* tp = (const float4*)pack_s + riu * (NB * 7);
        #pragma unroll
        for (int k = 0; k < NB; ++k) {
            v2f c2 = {cf[k], cf[k]};                    // splat: free via op_sel
            #pragma unroll
            for (int jo = 0; jo < 7; ++jo) {
                float4 tv = tp[k * 7 + jo];             // uniform -> broadcast
                t2[2 * jo]     = FMA2(c2, ((v2f){tv.x, tv.y}), t2[2 * jo]);
                t2[2 * jo + 1] = FMA2(c2, ((v2f){tv.z, tv.w}), t2[2 * jo + 1]);
            }
        }
        t2[6].x += 1.0f;     // + eye on t11 at jo == 3 (m=0)
        t2[7].y += 1.0f;     // + eye on t22 at jo == 3 (m=3)

        v2f nm2  = {0.f, 0.f};   // {nmu, nml}
        v2f ncu2 = {0.f, 0.f};   // horizontal-add at end
        v2f ncl2 = {0.f, 0.f};
        v2f ncs2 = {0.f, 0.f};
        #pragma unroll
        for (int jo = 0; jo < 7; ++jo) {
            const int jj = riu + jo;                    // 0..13 < NJJ
            float m_ = vsb[0 * VSV + jj * VSJ + lane];
            float n_ = vsb[1 * VSV + jj * VSJ + lane];
            float u_ = vsb[2 * VSV + jj * VSJ + lane];
            float l_ = vsb[3 * VSV + jj * VSJ + lane];
            float s_ = vsb[4 * VSV + jj * VSJ + lane];
            float A  = t2[2 * jo].x,     Bv = t2[2 * jo].y;
            float C  = t2[2 * jo + 1].x, D  = t2[2 * jo + 1].y;
            v2f AC = {A, C}, BD = {Bv, D}, AB = {A, Bv}, CD = {C, D};
            v2f us = {u_, s_}, sl = {s_, l_};
            nm2 = FMA2(AC, ((v2f){m_, m_}), nm2);       // {A*m, C*m}
            nm2 = FMA2(BD, ((v2f){n_, n_}), nm2);       // {B*n, D*n}
            v2f e = FMA2(((v2f){Bv, Bv}), sl, ((v2f){A, A}) * us);  // {e1,e2}
            v2f f = FMA2(((v2f){D, D}),  sl, ((v2f){C, C}) * us);   // {f1,f2}
            ncu2 = FMA2(AB, e, ncu2);                   // A*e1 + B*e2
            ncl2 = FMA2(CD, f, ncl2);                   // C*f1 + D*f2
            ncs2 = FMA2(CD, e, ncs2);                   // C*e1 + D*e2
        }
        float nmu  = nm2.x + ((rr == 0) ? ctl0 : ctl1);
        float nml  = nm2.y + ((rr == 0) ? ctl2 : ctl3);
        float ncuv = ncu2.x + ncu2.y + elup1f(log_noise[iuc]);
        float nclv = ncl2.x + ncl2.y + elup1f(log_noise[LOD + iuc]);
        float ncsv = ncs2.x + ncs2.y;
        onm[rr] = nmu; onl[rr] = nml; ouv[rr] = ncuv; olv[rr] = nclv; osv[rr] = ncsv;
    }
    __syncthreads();   // bar4: all reads of pack_s done -> overlay ost

    // ---------------- phase E: ost staging + float4 flush -------------------
    float* ost = ovl;                    // [t5][ri][b], overlays pack
    #pragma unroll
    for (int rr = 0; rr < 2; ++rr) {
        const int ri = 2 * wv + rr;
        ost[0 * OST_PLANE + ri * 65 + lane] = onm[rr];
        ost[1 * OST_PLANE + ri * 65 + lane] = onl[rr];
        ost[2 * OST_PLANE + ri * 65 + lane] = ouv[rr];
        ost[3 * OST_PLANE + ri * 65 + lane] = olv[rr];
        ost[4 * OST_PLANE + ri * 65 + lane] = osv[rr];
    }
    __syncthreads();   // bar5

    // float4 flush: 640 stores total, 16B-aligned (i0 % 8 == 0)
    for (int idx = tid; idx < 5 * 64 * 2; idx += 256) {
        int q   = idx & 1;
        int blc = (idx >> 1) & 63;
        int t5  = idx >> 7;
        if (i0 + q * 4 + 3 >= LOD) continue;     // only rg7, q=1
        int bb = b0 + blc;
        int ro = q * 4;
        float4 v;
        v.x = ost[t5 * OST_PLANE + (ro + 0) * 65 + blc];
        v.y = ost[t5 * OST_PLANE + (ro + 1) * 65 + blc];
        v.z = ost[t5 * OST_PLANE + (ro + 2) * 65 + blc];
        v.w = ost[t5 * OST_PLANE + (ro + 3) * 65 + blc];
        float* bp;
        if (t5 == 0)      bp = out + bb * LSD + i0;
        else if (t5 == 1) bp = out + bb * LSD + LOD + i0;
        else if (t5 == 2) bp = out + NM_SZ + bb * LOD + i0;
        else if (t5 == 3) bp = out + NM_SZ + NC_SZ + bb * LOD + i0;
        else              bp = out + NM_SZ + 2 * NC_SZ + bb * LOD + i0;
        *(float4*)(bp + ro) = v;
    }
}

extern "C" void kernel_launch(void* const* d_in, const int* in_sizes, int n_in,
                              void* d_out, int out_size, void* d_ws, size_t ws_size,
                              hipStream_t stream) {
    (void)in_sizes; (void)n_in; (void)out_size; (void)d_ws; (void)ws_size;
    const float* pm        = (const float*)d_in[0];
    const float* cu        = (const float*)d_in[1];
    const float* cl        = (const float*)d_in[2];
    const float* cs        = (const float*)d_in[3];
    const float* action    = (const float*)d_in[4];
    const float* tm11      = (const float*)d_in[5];
    const float* tm12      = (const float*)d_in[6];
    const float* tm21      = (const float*)d_in[7];
    const float* tm22      = (const float*)d_in[8];
    const float* log_noise = (const float*)d_in[9];
    const float* w_coef    = (const float*)d_in[10];
    const float* b_coef    = (const float*)d_in[11];
    const float* w_c1      = (const float*)d_in[12];
    const float* b_c1      = (const float*)d_in[13];
    const float* w_c2      = (const float*)d_in[14];
    const float* b_c2      = (const float*)d_in[15];

    hipLaunchKernelGGL(k_fused, dim3(1024), dim3(256), 0, stream,
                       pm, cu, cl, cs, action, tm11, tm12, tm21, tm22,
                       log_noise, w_coef, b_coef, w_c1, b_c1, w_c2, b_c2,
                       (float*)d_out);
}

// Round 7
// 117.213 us; speedup vs baseline: 3.8342x; 1.0038x over previous
//
#include <hip/hip_runtime.h>
#include <math.h>

// Problem constants
#define BATCH 8192
#define LOD 60
#define LSD 120
#define AD 10
#define NB 15
#define BW 3
#define H 60

// Output layout (floats)
#define NM_SZ (BATCH * LSD)   // next_mean 983040
#define NC_SZ (BATCH * LOD)   // 491520 each for ncu/ncl/ncs

// Banded tm pack in workspace: [i][k][jo][m], row stride 448 floats (1792 B,
// 64B-aligned) so the compiler can batch s_load_dwordx8/x16.
#define TMBG_STRIDE 448
#define TMBG_ROW 420                  // NB * 7 * 4 valid floats per row
#define TMBG_FLOATS (LOD * TMBG_STRIDE)   // 26880

// Geometry: 128 batch-groups (64 batches) x 8 row-groups (8 rows) = 1024 blocks.
#define RGS 8
#define RG_ROWS 8
#define NJJ 16                        // 8 + 2*BW = 14, padded to pow2
#define VSJ 65
#define VSV (NJJ * VSJ)               // 1040 floats per staged plane
#define VS_FLOATS (5 * VSV)           // 5200 @ ovl[0]
// region X @ 5200: phase A/B = coef(960)+hid(3900)=4860; phase D/E = ost(2600)
#define COEF_OFF VS_FLOATS
#define HID_OFF (VS_FLOATS + NB * 64)
#define OST_OFF VS_FLOATS
#define OST_PLANE (RG_ROWS * 65)      // 520
#define OVL_FLOATS (VS_FLOATS + 4860) // 10060 floats = 40.24 KB -> 4 blocks/CU

typedef float v2f __attribute__((ext_vector_type(2)));
#define FMA2(a, b, c) __builtin_elementwise_fma((a), (b), (c))

__device__ __forceinline__ float elup1f(float x) {
    return x < 0.0f ? __expf(x) : x + 1.0f;
}

// ---------------------------------------------------------------------------
// Prepass: banded tm pack -> workspace (26880 floats, 105 blocks)
// ---------------------------------------------------------------------------
__global__ __launch_bounds__(256) void k_pack(
    const float* __restrict__ tm11, const float* __restrict__ tm12,
    const float* __restrict__ tm21, const float* __restrict__ tm22,
    float* __restrict__ tmbg)
{
    int idx = blockIdx.x * 256 + threadIdx.x;
    if (idx >= TMBG_FLOATS) return;
    int i = idx / TMBG_STRIDE;
    int r = idx - i * TMBG_STRIDE;
    float val = 0.0f;
    if (r < TMBG_ROW) {
        int k  = r / 28;
        int z  = r - k * 28;
        int jo = z >> 2;
        int m  = z & 3;
        int j  = i - BW + jo;
        const float* tmm = (m == 0) ? tm11 : (m == 1) ? tm12 : (m == 2) ? tm21 : tm22;
        if (j >= 0 && j < LOD) val = tmm[k * (LOD * LOD) + i * LOD + j];
    }
    tmbg[idx] = val;
}

// ---------------------------------------------------------------------------
// Main fused kernel (3 barriers; mixing weights via uniform scalar loads)
// ---------------------------------------------------------------------------
__global__ __launch_bounds__(256, 4) void k_fused(
    const float* __restrict__ pm, const float* __restrict__ cu,
    const float* __restrict__ cl, const float* __restrict__ cs,
    const float* __restrict__ action,
    const float* __restrict__ log_noise,
    const float* __restrict__ w_coef, const float* __restrict__ b_coef,
    const float* __restrict__ w_c1, const float* __restrict__ b_c1,
    const float* __restrict__ w_c2, const float* __restrict__ b_c2,
    const float* __restrict__ tmbg,
    float* __restrict__ out)
{
    __shared__ __align__(16) float ovl[OVL_FLOATS];  // 40.24 KB

    const int tid  = threadIdx.x;
    const int lane = tid & 63;
    const int wv   = __builtin_amdgcn_readfirstlane(tid >> 6);

    // XCD-grouped swizzle: the 8 rg-blocks of one bg share one XCD's L2.
    const int bid  = blockIdx.x;            // 1024 = 8 XCDs * 128
    const int xcd  = bid & 7;
    const int slot = bid >> 3;              // 0..127
    const int bg   = xcd * 16 + (slot >> 3);
    const int rg   = slot & 7;
    const int b0   = bg * 64;
    const int i0   = rg * RG_ROWS;

    float* vsb   = ovl;                  // [v][jj][b], stride 65
    float* coefL = ovl + COEF_OFF;       // phase A/B only
    float* hid_s = ovl + HID_OFF;        // phase A/B only

    // ---------------- T14: issue vs loads at the very top ------------------
    float vr[20];
    {
        const int jj  = tid & 15;
        const int j   = i0 - BW + jj;
        const bool jok = (j >= 0) && (j < LOD);
        #pragma unroll
        for (int z = 0; z < 20; ++z) {
            const int idx = z * 256 + tid;
            const int blc = (idx >> 4) & 63;
            const int bb  = b0 + blc;
            float val = 0.0f;
            if (jok) {
                const int v = z >> 2;                  // compile-time per z
                if (v == 0)      val = pm[bb * LSD + j];
                else if (v == 1) val = pm[bb * LSD + LOD + j];
                else if (v == 2) val = cu[bb * LOD + j];
                else if (v == 3) val = cl[bb * LOD + j];
                else             val = cs[bb * LOD + j];
            }
            vr[z] = val;
        }
    }

    // ---------------- phase A: logits + shared hidden layer ----------------
    {
        const int k0 = wv, k1 = wv + 4, k2 = wv + 8;
        const int k3 = (wv < 3) ? wv + 12 : 14;     // wave 3: dummy stream
        const float4* pmv = (const float4*)(pm + (size_t)(b0 + lane) * LSD);
        const float4* w0 = (const float4*)(w_coef + k0 * LSD);
        const float4* w1 = (const float4*)(w_coef + k1 * LSD);
        const float4* w2 = (const float4*)(w_coef + k2 * LSD);
        const float4* w3 = (const float4*)(w_coef + k3 * LSD);
        v2f a0 = {0.f, 0.f}, a1 = {0.f, 0.f}, a2 = {0.f, 0.f}, a3 = {0.f, 0.f};
        #pragma unroll 6
        for (int d = 0; d < LSD / 4; ++d) {
            float4 p = pmv[d];
            v2f plo = {p.x, p.y}, phi = {p.z, p.w};   // adjacent regs: zero-move pk
            float4 u0 = w0[d], u1 = w1[d], u2 = w2[d], u3 = w3[d];
            a0 = FMA2(plo, ((v2f){u0.x, u0.y}), a0);
            a0 = FMA2(phi, ((v2f){u0.z, u0.w}), a0);
            a1 = FMA2(plo, ((v2f){u1.x, u1.y}), a1);
            a1 = FMA2(phi, ((v2f){u1.z, u1.w}), a1);
            a2 = FMA2(plo, ((v2f){u2.x, u2.y}), a2);
            a2 = FMA2(phi, ((v2f){u2.z, u2.w}), a2);
            a3 = FMA2(plo, ((v2f){u3.x, u3.y}), a3);
            a3 = FMA2(phi, ((v2f){u3.z, u3.w}), a3);
        }
        coefL[k0 * 64 + lane] = a0.x + a0.y + b_coef[k0];
        coefL[k1 * 64 + lane] = a1.x + a1.y + b_coef[k1];
        coefL[k2 * 64 + lane] = a2.x + a2.y + b_coef[k2];
        if (wv < 3) coefL[k3 * 64 + lane] = a3.x + a3.y + b_coef[k3];
    }
    {   // hidden layer, shared: wave wv owns h in [15wv, 15wv+15)
        v2f av2[5];
        const float2* a2p = (const float2*)(action + (size_t)(b0 + lane) * AD);
        #pragma unroll
        for (int z = 0; z < 5; ++z) { float2 t2 = a2p[z]; av2[z] = (v2f){t2.x, t2.y}; }
        #pragma unroll
        for (int q = 0; q < 15; ++q) {
            int h = wv * 15 + q;
            v2f acc2 = {0.f, 0.f};
            #pragma unroll
            for (int z = 0; z < 5; ++z)
                acc2 = FMA2(av2[z], *(const v2f*)(w_c1 + h * AD + 2 * z), acc2);
            float acc = acc2.x + acc2.y + b_c1[h];
            hid_s[h * 65 + lane] = fmaxf(acc, 0.0f);
        }
    }
    __syncthreads();   // bar1: logits + hidden visible

    // ---------------- phase B: softmax + control (reads coef/hid) ----------
    float cf[NB];
    {
        float mx = -1e30f;
        #pragma unroll
        for (int k = 0; k < NB; ++k) { cf[k] = coefL[k * 64 + lane]; mx = fmaxf(mx, cf[k]); }
        float sm = 0.0f;
        #pragma unroll
        for (int k = 0; k < NB; ++k) { cf[k] = __expf(cf[k] - mx); sm += cf[k]; }
        float inv = 1.0f / sm;
        #pragma unroll
        for (int k = 0; k < NB; ++k) cf[k] *= inv;
    }
    const int r0g = i0 + 2 * wv;
    const int c0  = (r0g < LOD) ? r0g : LOD - 1;        // rg7/wv3 clamp
    const int c1  = (r0g + 1 < LOD) ? r0g + 1 : LOD - 1;
    float ctl0 = b_c2[c0], ctl1 = b_c2[c1];
    float ctl2 = b_c2[LOD + c0], ctl3 = b_c2[LOD + c1];
    #pragma unroll 4
    for (int h = 0; h < H; ++h) {
        float hv = hid_s[h * 65 + lane];                // lane-stride-1
        ctl0 = fmaf(hv, w_c2[c0 * H + h], ctl0);        // uniform -> s_load
        ctl1 = fmaf(hv, w_c2[c1 * H + h], ctl1);
        ctl2 = fmaf(hv, w_c2[(LOD + c0) * H + h], ctl2);
        ctl3 = fmaf(hv, w_c2[(LOD + c1) * H + h], ctl3);
    }

    // ---------------- phase C: vs LDS writes (region disjoint from X) ------
    {
        const int jj = tid & 15;
        #pragma unroll
        for (int z = 0; z < 20; ++z) {
            const int idx = z * 256 + tid;
            const int blc = (idx >> 4) & 63;
            vsb[(z >> 2) * VSV + jj * VSJ + blc] = vr[z];   // 2-way alias: free
        }
    }
    __syncthreads();   // bar2: vs staged; all coef/hid reads done

    // ---------------- phase D: mixing (scalar loads) + banded products -----
    float onm[2], onl[2], ouv[2], olv[2], osv[2];
    #pragma unroll
    for (int rr = 0; rr < 2; ++rr) {
        const int riu = 2 * wv + rr;                    // wave-uniform
        const int iu  = i0 + riu;
        const int iuc = (iu < LOD) ? iu : LOD - 1;      // rg7: garbage row, skipped

        // mixing: weights via uniform scalar loads on the SMEM pipe
        const float* tpg = tmbg + (size_t)iuc * TMBG_STRIDE;
        v2f t2[14];
        #pragma unroll
        for (int z = 0; z < 14; ++z) t2[z] = (v2f){0.f, 0.f};
        #pragma unroll
        for (int k = 0; k < NB; ++k) {
            v2f c2 = {cf[k], cf[k]};                    // splat: free via op_sel
            #pragma unroll
            for (int jo = 0; jo < 7; ++jo) {
                v2f w01 = *(const v2f*)(tpg + k * 28 + jo * 4);      // s_load
                v2f w23 = *(const v2f*)(tpg + k * 28 + jo * 4 + 2);  // s_load
                t2[2 * jo]     = FMA2(c2, w01, t2[2 * jo]);
                t2[2 * jo + 1] = FMA2(c2, w23, t2[2 * jo + 1]);
            }
        }
        t2[6].x += 1.0f;     // + eye on t11 at jo == 3 (m=0)
        t2[7].y += 1.0f;     // + eye on t22 at jo == 3 (m=3)

        // banded products: scalar form (round-5 proven codegen)
        float nmu = 0.f, nml = 0.f, ncuv = 0.f, nclv = 0.f, ncsv = 0.f;
        #pragma unroll
        for (int jo = 0; jo < 7; ++jo) {
            const int jj = riu + jo;                    // 0..13 < NJJ
            float m_ = vsb[0 * VSV + jj * VSJ + lane];
            float n_ = vsb[1 * VSV + jj * VSJ + lane];
            float u_ = vsb[2 * VSV + jj * VSJ + lane];
            float l_ = vsb[3 * VSV + jj * VSJ + lane];
            float s_ = vsb[4 * VSV + jj * VSJ + lane];
            float A  = t2[2 * jo].x,     Bv = t2[2 * jo].y;
            float C  = t2[2 * jo + 1].x, D  = t2[2 * jo + 1].y;
            nmu = fmaf(A, m_, nmu);  nmu = fmaf(Bv, n_, nmu);
            nml = fmaf(C, m_, nml);  nml = fmaf(D, n_, nml);
            float e1 = fmaf(Bv, s_, A * u_);
            float e2 = fmaf(Bv, l_, A * s_);
            float f1 = fmaf(D, s_, C * u_);
            float f2 = fmaf(D, l_, C * s_);
            ncuv = fmaf(A, e1, ncuv);  ncuv = fmaf(Bv, e2, ncuv);
            nclv = fmaf(C, f1, nclv);  nclv = fmaf(D, f2, nclv);
            ncsv = fmaf(C, e1, ncsv);  ncsv = fmaf(D, e2, ncsv);
        }
        ncuv += elup1f(log_noise[iuc]);
        nclv += elup1f(log_noise[LOD + iuc]);
        nmu  += (rr == 0) ? ctl0 : ctl1;
        nml  += (rr == 0) ? ctl2 : ctl3;
        onm[rr] = nmu; onl[rr] = nml; ouv[rr] = ncuv; olv[rr] = nclv; osv[rr] = ncsv;
    }

    // ---------------- phase E: ost staging (overlays coef/hid) -------------
    // All reads of region X (coefL/hid_s) finished before bar2 -> safe now.
    float* ost = ovl + OST_OFF;
    #pragma unroll
    for (int rr = 0; rr < 2; ++rr) {
        const int ri = 2 * wv + rr;
        ost[0 * OST_PLANE + ri * 65 + lane] = onm[rr];
        ost[1 * OST_PLANE + ri * 65 + lane] = onl[rr];
        ost[2 * OST_PLANE + ri * 65 + lane] = ouv[rr];
        ost[3 * OST_PLANE + ri * 65 + lane] = olv[rr];
        ost[4 * OST_PLANE + ri * 65 + lane] = osv[rr];
    }
    __syncthreads();   // bar3

    // float4 flush: 640 stores total, 16B-aligned (i0 % 8 == 0)
    for (int idx = tid; idx < 5 * 64 * 2; idx += 256) {
        int q   = idx & 1;
        int blc = (idx >> 1) & 63;
        int t5  = idx >> 7;
        if (i0 + q * 4 + 3 >= LOD) continue;     // only rg7, q=1
        int bb = b0 + blc;
        int ro = q * 4;
        float4 v;
        v.x = ost[t5 * OST_PLANE + (ro + 0) * 65 + blc];
        v.y = ost[t5 * OST_PLANE + (ro + 1) * 65 + blc];
        v.z = ost[t5 * OST_PLANE + (ro + 2) * 65 + blc];
        v.w = ost[t5 * OST_PLANE + (ro + 3) * 65 + blc];
        float* bp;
        if (t5 == 0)      bp = out + bb * LSD + i0;
        else if (t5 == 1) bp = out + bb * LSD + LOD + i0;
        else if (t5 == 2) bp = out + NM_SZ + bb * LOD + i0;
        else if (t5 == 3) bp = out + NM_SZ + NC_SZ + bb * LOD + i0;
        else              bp = out + NM_SZ + 2 * NC_SZ + bb * LOD + i0;
        *(float4*)(bp + ro) = v;
    }
}

extern "C" void kernel_launch(void* const* d_in, const int* in_sizes, int n_in,
                              void* d_out, int out_size, void* d_ws, size_t ws_size,
                              hipStream_t stream) {
    (void)in_sizes; (void)n_in; (void)out_size; (void)ws_size;
    const float* pm        = (const float*)d_in[0];
    const float* cu        = (const float*)d_in[1];
    const float* cl        = (const float*)d_in[2];
    const float* cs        = (const float*)d_in[3];
    const float* action    = (const float*)d_in[4];
    const float* tm11      = (const float*)d_in[5];
    const float* tm12      = (const float*)d_in[6];
    const float* tm21      = (const float*)d_in[7];
    const float* tm22      = (const float*)d_in[8];
    const float* log_noise = (const float*)d_in[9];
    const float* w_coef    = (const float*)d_in[10];
    const float* b_coef    = (const float*)d_in[11];
    const float* w_c1      = (const float*)d_in[12];
    const float* b_c1      = (const float*)d_in[13];
    const float* w_c2      = (const float*)d_in[14];
    const float* b_c2      = (const float*)d_in[15];

    float* tmbg = (float*)d_ws;   // 26880 floats = 107.5 KB

    hipLaunchKernelGGL(k_pack, dim3((TMBG_FLOATS + 255) / 256), dim3(256), 0, stream,
                       tm11, tm12, tm21, tm22, tmbg);

    hipLaunchKernelGGL(k_fused, dim3(1024), dim3(256), 0, stream,
                       pm, cu, cl, cs, action, log_noise,
                       w_coef, b_coef, w_c1, b_c1, w_c2, b_c2, tmbg,
                       (float*)d_out);
}